// Round 12
// baseline (147.167 us; speedup 1.0000x reference)
//
#include <hip/hip_runtime.h>
#include <math.h>

#define BQ 8
#define MQ 64
#define KTOP 10
#define EPSQ 1e-7f
#define APB 512   // anchors per decode block (256 threads x 2) -> 536 blocks
#define MBUF 1344 // >= bpb*KTOP = 670 for N=34000

__device__ __forceinline__ float frcp(float x) { return __builtin_amdgcn_rcpf(x); }

typedef float __attribute__((ext_vector_type(4))) f32x4;

// nontemporal 16B global read: boxes is single-use-per-iteration and the
// harness poison sweep evicts it anyway — skip L2 allocation.
__device__ __forceinline__ f32x4 ldnt4(const float* p) {
  return __builtin_nontemporal_load((const f32x4*)p);
}

// ---------------- kernel 1: decode via SIDE-TILE staging (R9 structure,
// best-measured 140.5us) + nontemporal staging loads ----------------
__global__ __launch_bounds__(256) void decode_topk_kernel(
    const float* __restrict__ boxes, const float* __restrict__ scores,
    const float* __restrict__ targets, unsigned int* __restrict__ iou_bits,
    uint2* __restrict__ cand, float* __restrict__ bcePartial,
    unsigned int* __restrict__ ctr, int N, int bpb) {
  const int tid = threadIdx.x;
  const int b = blockIdx.x / bpb;
  const int blk = blockIdx.x - b * bpb;
  const int a0 = blk * APB;
  const int w = tid >> 6;
  const int l = tid & 63;

  // 32KB stage tile, ALIASED with phase-2/3 heaps (temporally disjoint).
  __shared__ __align__(16) char u_raw[16 * APB * sizeof(float)];  // 32768
  float(*tile)[APB] = (float(*)[APB])u_raw;
  float* s_hv = (float*)u_raw;              // 10240B
  int* s_hi = (int*)(u_raw + 10240);        // 10240B
  uint2* s_mg = (uint2*)(u_raw + 20480);    // 5120B
  __shared__ float4 s_sv[APB];              // survivors: live ph1-end..ph2
  __shared__ float s_at[APB];
  __shared__ int s_ix[APB];
  __shared__ int s_cnt;
  __shared__ float s_bce;
  if (tid == 0) { s_cnt = 0; s_bce = 0.f; }
  if (blockIdx.x == 0 && tid == 0) *ctr = 0u;  // merge-done ctr; stream-ordered
  __syncthreads();

  const size_t Ns = (size_t)N;
  const int n0 = a0 + 2 * tid;  // this thread's 2 anchors
  const bool tail = (a0 + APB > N);

  // ---- early BCE + iou init for both anchors ----
  float bce0 = 0.f;
  if (n0 < N) {
    const size_t i = (size_t)b * N + n0;
    if (n0 + 1 < N && ((i & 1) == 0)) {
      iou_bits[i] = 0u; iou_bits[i + 1] = 0u;
      float2 sc = *(const float2*)(scores + i);
      bce0 = fmaxf(sc.x, 0.f) + log1pf(__expf(-fabsf(sc.x))) +
             fmaxf(sc.y, 0.f) + log1pf(__expf(-fabsf(sc.y)));
    } else if (n0 + 1 < N) {
      iou_bits[i] = 0u; iou_bits[i + 1] = 0u;
      float sa = scores[i], sb = scores[i + 1];
      bce0 = fmaxf(sa, 0.f) + log1pf(__expf(-fabsf(sa))) +
             fmaxf(sb, 0.f) + log1pf(__expf(-fabsf(sb)));
    } else {
      iou_bits[i] = 0u;
      float sc = scores[i];
      bce0 = fmaxf(sc, 0.f) + log1pf(__expf(-fabsf(sc)));
    }
  }

  // ---- phase 1: 4 sides; per side: coalesced nt-stage (2KB/row) -> EV x2 ----
  const int tcol = 2 * tid;
  float ev_a[4], ev_b[4];  // statically indexed (full unroll)
#pragma unroll
  for (int s = 0; s < 4; ++s) {
    const float* gside = boxes + (size_t)(b * 64 + s * 16) * Ns;
    if (!tail) {
#pragma unroll
      for (int k = 0; k < 8; ++k) {
        int idx = tid + (k << 8);
        int r = idx >> 7;
        int c = (idx & 127) << 2;
        f32x4 v = ldnt4(gside + (size_t)r * Ns + a0 + c);
        *(f32x4*)&tile[r][c] = v;
      }
    } else {
#pragma unroll
      for (int k = 0; k < 8; ++k) {
        int idx = tid + (k << 8);
        int r = idx >> 7;
        int c = (idx & 127) << 2;
        int gc = a0 + c;
        if (gc > N - 4) gc = N - 4;  // dup-clamp: invalid anchors pred-guarded
        if (gc < 0) gc = 0;
        f32x4 v = ldnt4(gside + (size_t)r * Ns + gc);
        *(f32x4*)&tile[r][c] = v;
      }
    }
    __syncthreads();
    // two interleaved softmax-EV chains from LDS (float2 per row)
    float2 x0 = *(const float2*)&tile[0][tcol];
    float2 x1 = *(const float2*)&tile[1][tcol];
    float2 x2 = *(const float2*)&tile[2][tcol];
    float2 x3 = *(const float2*)&tile[3][tcol];
    float2 x4 = *(const float2*)&tile[4][tcol];
    float2 x5 = *(const float2*)&tile[5][tcol];
    float2 x6 = *(const float2*)&tile[6][tcol];
    float2 x7 = *(const float2*)&tile[7][tcol];
    float2 x8 = *(const float2*)&tile[8][tcol];
    float2 x9 = *(const float2*)&tile[9][tcol];
    float2 x10 = *(const float2*)&tile[10][tcol];
    float2 x11 = *(const float2*)&tile[11][tcol];
    float2 x12 = *(const float2*)&tile[12][tcol];
    float2 x13 = *(const float2*)&tile[13][tcol];
    float2 x14 = *(const float2*)&tile[14][tcol];
    float2 x15 = *(const float2*)&tile[15][tcol];
    float mxa = fmaxf(fmaxf(fmaxf(fmaxf(x0.x, x1.x), fmaxf(x2.x, x3.x)),
                            fmaxf(fmaxf(x4.x, x5.x), fmaxf(x6.x, x7.x))),
                      fmaxf(fmaxf(fmaxf(x8.x, x9.x), fmaxf(x10.x, x11.x)),
                            fmaxf(fmaxf(x12.x, x13.x), fmaxf(x14.x, x15.x))));
    float mxb = fmaxf(fmaxf(fmaxf(fmaxf(x0.y, x1.y), fmaxf(x2.y, x3.y)),
                            fmaxf(fmaxf(x4.y, x5.y), fmaxf(x6.y, x7.y))),
                      fmaxf(fmaxf(fmaxf(x8.y, x9.y), fmaxf(x10.y, x11.y)),
                            fmaxf(fmaxf(x12.y, x13.y), fmaxf(x14.y, x15.y))));
    float sa = 0.f, wa = 0.f, sb = 0.f, wb = 0.f, e;
#define STEP(K, XK)                                    \
    e = __expf(XK.x - mxa); sa += e; wa += (float)K * e; \
    e = __expf(XK.y - mxb); sb += e; wb += (float)K * e;
    STEP(0, x0) STEP(1, x1) STEP(2, x2) STEP(3, x3)
    STEP(4, x4) STEP(5, x5) STEP(6, x6) STEP(7, x7)
    STEP(8, x8) STEP(9, x9) STEP(10, x10) STEP(11, x11)
    STEP(12, x12) STEP(13, x13) STEP(14, x14) STEP(15, x15)
#undef STEP
    ev_a[s] = wa * frcp(sa);
    ev_b[s] = wb * frcp(sb);
    __syncthreads();  // tile reads done before restage / heap use
  }

  // ---- screen + ballot compaction (two rounds: anchor n0, n0+1) ----
  {
    bool pa = false, pb = false;
    float ata = 0.f, atb = 0.f;
    if (n0 < N) {
      float w1 = ev_a[2] - ev_a[0], h1 = ev_a[3] - ev_a[1];
      if (w1 > 0.f && h1 > 0.f) { pa = true; ata = atanf(w1 * frcp(h1 + EPSQ)); }
    }
    if (n0 + 1 < N) {
      float w1 = ev_b[2] - ev_b[0], h1 = ev_b[3] - ev_b[1];
      if (w1 > 0.f && h1 > 0.f) { pb = true; atb = atanf(w1 * frcp(h1 + EPSQ)); }
    }
    unsigned long long ma = __ballot(pa);
    int ca = __popcll(ma);
    int sa_ = 0;
    if (l == 0 && ca) sa_ = atomicAdd(&s_cnt, ca);
    sa_ = __shfl(sa_, 0, 64);
    if (pa) {
      int pos = sa_ + __popcll(ma & ((1ull << l) - 1ull));
      s_sv[pos] = make_float4(ev_a[0], ev_a[1], ev_a[2], ev_a[3]);
      s_at[pos] = ata;
      s_ix[pos] = n0;
    }
    unsigned long long mb = __ballot(pb);
    int cb = __popcll(mb);
    int sb_ = 0;
    if (l == 0 && cb) sb_ = atomicAdd(&s_cnt, cb);
    sb_ = __shfl(sb_, 0, 64);
    if (pb) {
      int pos = sb_ + __popcll(mb & ((1ull << l) - 1ull));
      s_sv[pos] = make_float4(ev_b[0], ev_b[1], ev_b[2], ev_b[3]);
      s_at[pos] = atb;
      s_ix[pos] = n0 + 1;
    }
  }
#pragma unroll
  for (int d = 1; d < 64; d <<= 1) bce0 += __shfl_xor(bce0, d, 64);
  if (l == 0) atomicAdd(&s_bce, bce0);
  __syncthreads();
  const int nsurv = s_cnt;
  if (tid == 0) bcePartial[blockIdx.x] = s_bce;  // always written: no memset

  // ---- phase 2: lane = target; wave w scans its survivor quarter ----
  const float4 t = ((const float4*)targets)[b * MQ + l];
  const float x21 = t.x, y21 = t.y, x22 = t.z, y22 = t.w;
  const float w2 = x22 - x21, h2 = y22 - y21;
  const float atan_t = atanf(w2 * frcp(h2 + EPSQ));
  const float area2 = w2 * h2, sumx2 = x21 + x22, sumy2 = y21 + y22;
  const float CPI = 4.0f / (float)(M_PI * M_PI);

  float hv0 = 0.f, hv1 = 0.f, hv2 = 0.f, hv3 = 0.f, hv4 = 0.f;
  float hv5 = 0.f, hv6 = 0.f, hv7 = 0.f, hv8 = 0.f, hv9 = 0.f;
  int hi0 = 0, hi1 = 0, hi2 = 0, hi3 = 0, hi4 = 0;
  int hi5 = 0, hi6 = 0, hi7 = 0, hi8 = 0, hi9 = 0;

  const int qlen = (nsurv + 3) >> 2;
  const int j0 = w * qlen;
  const int j1 = min(nsurv, j0 + qlen);
  for (int j = j0; j < j1; ++j) {
    float4 p = s_sv[j];  // same addr across lanes -> LDS broadcast
    float pa = s_at[j];
    int ixj = s_ix[j];
    float x11 = p.x, y11 = p.y, x12 = p.z, y12 = p.w;
    float w1 = x12 - x11, h1 = y12 - y11;
    float iw = fmaxf(fminf(x12, x22) - fmaxf(x11, x21), 0.f);
    float ih = fmaxf(fminf(y12, y22) - fmaxf(y11, y21), 0.f);
    float inter = iw * ih;
    float uni = w1 * h1 + area2 - inter + EPSQ;
    float iou = inter * frcp(uni);
    float cw = fmaxf(x12, x22) - fminf(x11, x21);
    float ch = fmaxf(y12, y22) - fminf(y11, y21);
    float c2 = cw * cw + ch * ch + EPSQ;
    float dx = sumx2 - x11 - x12;
    float dy = sumy2 - y11 - y12;
    float rho2 = (dx * dx + dy * dy) * 0.25f;
    float da = atan_t - pa;
    float v = CPI * da * da;
    float alpha = v * frcp(v - iou + 1.f + EPSQ);
    float ciou = iou - rho2 * frcp(c2) - alpha * v;
    if (ciou > hv9) {
      float cv = ciou;
      int ci = ixj;
#define INS(vk, ik)                         \
  {                                         \
    bool gt = cv > vk;                      \
    float tv_ = vk; int ti_ = ik;           \
    vk = gt ? cv : vk; ik = gt ? ci : ik;   \
    cv = gt ? tv_ : cv; ci = gt ? ti_ : ci; \
  }
      INS(hv0, hi0) INS(hv1, hi1) INS(hv2, hi2) INS(hv3, hi3) INS(hv4, hi4)
      INS(hv5, hi5) INS(hv6, hi6) INS(hv7, hi7) INS(hv8, hi8) INS(hv9, hi9)
#undef INS
    }
  }
  const int hb = (w * MQ + l) * KTOP;
  s_hv[hb + 0] = hv0; s_hi[hb + 0] = hi0;
  s_hv[hb + 1] = hv1; s_hi[hb + 1] = hi1;
  s_hv[hb + 2] = hv2; s_hi[hb + 2] = hi2;
  s_hv[hb + 3] = hv3; s_hi[hb + 3] = hi3;
  s_hv[hb + 4] = hv4; s_hi[hb + 4] = hi4;
  s_hv[hb + 5] = hv5; s_hi[hb + 5] = hi5;
  s_hv[hb + 6] = hv6; s_hi[hb + 6] = hi6;
  s_hv[hb + 7] = hv7; s_hi[hb + 7] = hi7;
  s_hv[hb + 8] = hv8; s_hi[hb + 8] = hi8;
  s_hv[hb + 9] = hv9; s_hi[hb + 9] = hi9;
  __syncthreads();

  // ---- phase 3: wave 0, lane m: 4-way merge -> s_mg ----
  if (w == 0) {
    const int m = l;
    int p0 = 0, p1 = 0, p2 = 0, p3 = 0;
    for (int r = 0; r < KTOP; ++r) {
      float c0 = s_hv[(0 * MQ + m) * KTOP + p0];
      float c1 = s_hv[(1 * MQ + m) * KTOP + p1];
      float c2m = s_hv[(2 * MQ + m) * KTOP + p2];
      float c3 = s_hv[(3 * MQ + m) * KTOP + p3];
      float best = c0; int bw = 0;
      if (c1 > best) { best = c1; bw = 1; }
      if (c2m > best) { best = c2m; bw = 2; }
      if (c3 > best) { best = c3; bw = 3; }
      int psel = (bw == 0) ? p0 : (bw == 1) ? p1 : (bw == 2) ? p2 : p3;
      int bidx = s_hi[(bw * MQ + m) * KTOP + psel];
      s_mg[m * KTOP + r] = make_uint2(__float_as_uint(best), (unsigned)bidx);
      if (bw == 0) p0 = min(p0 + 1, KTOP - 1);
      else if (bw == 1) p1 = min(p1 + 1, KTOP - 1);
      else if (bw == 2) p2 = min(p2 + 1, KTOP - 1);
      else p3 = min(p3 + 1, KTOP - 1);
    }
  }
  __syncthreads();
  // copy-out: CONTIGUOUS per-block store (merge takes the strided read side)
  uint2* obase = cand + (size_t)(b * bpb + blk) * (MQ * KTOP);
  for (int sl = tid; sl < MQ * KTOP; sl += 256) obase[sl] = s_mg[sl];
}

// ---------------- exact top-10 of LDS buffer (wave 0 only) ----------------
__device__ __forceinline__ void select_top10(
    float* s_bv, int* s_bi, float* s_winv, int* s_wini,
    int* s_cnt, int c, int tid) {
  if (tid < 64) {
    for (int r = 0; r < KTOP; ++r) {
      float bv = 0.f;
      int bs = 0xffff;
      for (int sl = tid; sl < c; sl += 64) {
        float v = s_bv[sl];
        if (v > bv) { bv = v; bs = sl; }
      }
      unsigned long long key =
          ((unsigned long long)__float_as_uint(bv) << 32) | (unsigned int)bs;
#pragma unroll
      for (int d = 1; d < 64; d <<= 1) {
        unsigned long long o = __shfl_xor(key, d, 64);
        if (o > key) key = o;
      }
      if (tid == 0) {
        float wv = __uint_as_float((unsigned int)(key >> 32));
        int ws = (int)(key & 0xffffu);
        s_winv[r] = wv;
        if (wv > 0.f && ws != 0xffff) {
          s_wini[r] = s_bi[ws];
          s_bv[ws] = 0.f;
        } else {
          s_wini[r] = 0;
        }
      }
    }
    if (tid < KTOP) { s_bv[tid] = s_winv[tid]; s_bi[tid] = s_wini[tid]; }
    if (tid == 0) *s_cnt = KTOP;
  }
}

// ---------------- kernel 2: merge 67x10 per (b,m) -> top-10; scatter + exact delta;
// last block finalizes with a parallel reduction ----------------
__global__ __launch_bounds__(256) void merge_kernel(
    const uint2* __restrict__ cand, const float* __restrict__ scores,
    unsigned int* __restrict__ iou_bits, const float* __restrict__ bcePartial,
    float* __restrict__ mergePartial, unsigned int* __restrict__ ctr,
    float* __restrict__ out, int N, int bpb) {
  const int bm = blockIdx.x;
  const int b = bm >> 6;
  const int m = bm & 63;
  const int tid = threadIdx.x;
  const int l = tid & 63;
  const int NC = bpb * KTOP;  // 670 for N=34000

  __shared__ float s_bv[MBUF];
  __shared__ int s_bi[MBUF];
  __shared__ float s_winv[KTOP];
  __shared__ int s_wini[KTOP];
  __shared__ int s_cnt;
  __shared__ float s_d[3];
  __shared__ int s_last;
  __shared__ float s_acc[BQ * 3];  // finalize: {box_sum, npos, bce} per batch
  if (tid == 0) s_cnt = 0;
  if (tid < 3) s_d[tid] = 0.f;
  if (tid < BQ * 3) s_acc[tid] = 0.f;
  __syncthreads();

  // strided gather over decode blocks (cand in contiguous-per-block layout)
  for (int k2 = tid; k2 < NC; k2 += 256) {
    int blkk = k2 / KTOP;
    int r = k2 - blkk * KTOP;
    uint2 e = cand[((size_t)(b * bpb + blkk) * MQ + m) * KTOP + r];
    float v = __uint_as_float(e.x);
    bool p = v > 0.f;
    unsigned long long mask = __ballot(p);  // lane0 active whenever any lane is
    int cnt = __popcll(mask);
    int bslot = 0;
    if (l == 0 && cnt) bslot = atomicAdd(&s_cnt, cnt);
    bslot = __shfl(bslot, 0, 64);
    if (p) {
      int pos = bslot + __popcll(mask & ((1ull << l) - 1ull));
      s_bv[pos] = v;
      s_bi[pos] = (int)e.y;
    }
  }
  __syncthreads();
  int c = s_cnt;
  __syncthreads();
  if (c > KTOP) {
    select_top10(s_bv, s_bi, s_winv, s_wini, &s_cnt, c, tid);
    __syncthreads();
    c = KTOP;
  }
  if (tid < KTOP && tid < c) {
    float v = s_bv[tid];
    if (v > 0.f) {
      int ix = s_bi[tid];
      unsigned int vb = __float_as_uint(v);
      unsigned int old = atomicMax(&iou_bits[(size_t)b * N + ix], vb);
      if (old < vb) {  // raised this anchor's max: exact delta (telescopes)
        float vold = __uint_as_float(old);  // 0.f when old==0
        bool was = (old != 0u);
        atomicAdd(&s_d[0], was ? (vold - v) : (1.f - v));
        if (!was) atomicAdd(&s_d[1], 1.f);
        atomicAdd(&s_d[2], -scores[(size_t)b * N + ix] * (v - vold));
      }
    }
  }
  __syncthreads();
  if (tid == 0) {
    float4* mp = (float4*)(mergePartial + (size_t)bm * 4);
    *mp = make_float4(s_d[0], s_d[1], s_d[2], 0.f);  // always written
    __threadfence();                                  // release partials
    unsigned int done = atomicAdd(ctr, 1u);           // device-scope RMW
    s_last = (done == (unsigned)(gridDim.x - 1)) ? 1 : 0;
  }
  __syncthreads();
  if (s_last) {
    __threadfence();  // acquire: all other blocks' partials now visible
    volatile const float* mp = mergePartial;
    for (int i = tid; i < BQ * MQ; i += 256) {
      int bb = i >> 6;
      float a0 = mp[i * 4 + 0];
      float a1 = mp[i * 4 + 1];
      float a2 = mp[i * 4 + 2];
      atomicAdd(&s_acc[bb * 3 + 0], a0);
      atomicAdd(&s_acc[bb * 3 + 1], a1);
      atomicAdd(&s_acc[bb * 3 + 2], a2);
    }
    volatile const float* bp = bcePartial;
    for (int i = tid; i < BQ * bpb; i += 256) {
      int bb = i / bpb;
      atomicAdd(&s_acc[bb * 3 + 2], bp[i]);
    }
    __syncthreads();
    if (tid == 0) {
      float box = 0.f, obj = 0.f;
      for (int bb = 0; bb < BQ; ++bb) {
        float np = s_acc[bb * 3 + 1];
        box += (np > 0.f) ? s_acc[bb * 3 + 0] / fmaxf(np, 1.f) : 0.f;
        obj += s_acc[bb * 3 + 2] / (float)N;
      }
      out[0] = (7.5f * box + obj) / (float)BQ;
      out[1] = box;
      out[2] = obj;
    }
  }
}

extern "C" void kernel_launch(void* const* d_in, const int* in_sizes, int n_in,
                              void* d_out, int out_size, void* d_ws, size_t ws_size,
                              hipStream_t stream) {
  const float* boxes = (const float*)d_in[0];
  const float* scores = (const float*)d_in[1];
  const float* targets = (const float*)d_in[2];
  float* out = (float*)d_out;
  const int N = in_sizes[1] / BQ;  // scores is [B, N]

  const int bpb = (N + APB - 1) / APB;  // 67 for N=34000
  const int nblk = BQ * bpb;            // 536 decode blocks

  char* ws = (char*)d_ws;
  size_t cand_bytes = (size_t)BQ * bpb * MQ * KTOP * sizeof(uint2);
  size_t iou_bytes = (size_t)BQ * N * sizeof(unsigned int);
  size_t bce_bytes = (((size_t)nblk * sizeof(float)) + 255) & ~(size_t)255;
  size_t mp_bytes = (size_t)BQ * MQ * 4 * sizeof(float);

  uint2* cand = (uint2*)ws;                    ws += cand_bytes;
  unsigned int* iou_bits = (unsigned int*)ws;  ws += iou_bytes;
  float* bcePartial = (float*)ws;              ws += bce_bytes;
  float* mergePartial = (float*)ws;            ws += mp_bytes;
  unsigned int* ctr = (unsigned int*)ws;

  // 2 dispatches: no memset (always-written per-block partials; ctr zeroed by
  // decode which fully precedes merge by stream order), no finalize dispatch
  // (folded into merge's last block, parallel-reduced).
  decode_topk_kernel<<<nblk, 256, 0, stream>>>(boxes, scores, targets,
                                               iou_bits, cand, bcePartial, ctr, N, bpb);
  merge_kernel<<<BQ * MQ, 256, 0, stream>>>(cand, scores, iou_bits, bcePartial,
                                            mergePartial, ctr, out, N, bpb);
}

// Round 13
// 139.972 us; speedup vs baseline: 1.0514x; 1.0514x over previous
//
#include <hip/hip_runtime.h>
#include <math.h>

#define BQ 8
#define MQ 64
#define KTOP 10
#define EPSQ 1e-7f
#define APB 512   // anchors per decode block (256 threads x 2) -> 536 blocks (<=768 capacity)
#define MBUF 1344 // >= bpb*KTOP = 670 for N=34000

// FINAL (terminal) configuration — best measured: 140.5 us (round 9).
// Structural constraints at this plateau:
//  - 87 us: harness workspace re-poison fills (272 MB @ 80% HBM peak), fixed;
//    also sweeps L3 so boxes is always HBM-cold.
//  - ~47 us: decode = 70 MB cold-HBM read under a per-CU read-concurrency cap
//    (~64-96 lines in flight x ~900 ns) -> ~5-6 GB/s/CU independent of access
//    structure. Verified by 8 falsified variants (gather widths 4/8/16B,
//    barrier-staged, async global_load_lds x2, side-tile, LDS-free split,
//    4KB-run slab) all at 44-53 us with ~850 GB/s HBM, low VALU, low occ.
//  - ~9 us: merge + folded finalize (launch + latency floor).

__device__ __forceinline__ float frcp(float x) { return __builtin_amdgcn_rcpf(x); }

// ---------------- kernel 1: decode via SIDE-TILE staging ----------------
__global__ __launch_bounds__(256) void decode_topk_kernel(
    const float* __restrict__ boxes, const float* __restrict__ scores,
    const float* __restrict__ targets, unsigned int* __restrict__ iou_bits,
    uint2* __restrict__ cand, float* __restrict__ bcePartial,
    unsigned int* __restrict__ ctr, int N, int bpb) {
  const int tid = threadIdx.x;
  const int b = blockIdx.x / bpb;
  const int blk = blockIdx.x - b * bpb;
  const int a0 = blk * APB;
  const int w = tid >> 6;
  const int l = tid & 63;

  // 32KB stage tile, ALIASED with phase-2/3 heaps (temporally disjoint).
  __shared__ __align__(16) char u_raw[16 * APB * sizeof(float)];  // 32768
  float(*tile)[APB] = (float(*)[APB])u_raw;
  float* s_hv = (float*)u_raw;              // 10240B
  int* s_hi = (int*)(u_raw + 10240);        // 10240B
  uint2* s_mg = (uint2*)(u_raw + 20480);    // 5120B
  __shared__ float4 s_sv[APB];              // survivors: live ph1-end..ph2
  __shared__ float s_at[APB];
  __shared__ int s_ix[APB];
  __shared__ int s_cnt;
  __shared__ float s_bce;
  if (tid == 0) { s_cnt = 0; s_bce = 0.f; }
  if (blockIdx.x == 0 && tid == 0) *ctr = 0u;  // merge-done ctr; stream-ordered
  __syncthreads();

  const size_t Ns = (size_t)N;
  const int n0 = a0 + 2 * tid;  // this thread's 2 anchors
  const bool tail = (a0 + APB > N);

  // ---- early BCE + iou init for both anchors ----
  float bce0 = 0.f;
  if (n0 < N) {
    const size_t i = (size_t)b * N + n0;
    if (n0 + 1 < N && ((i & 1) == 0)) {
      iou_bits[i] = 0u; iou_bits[i + 1] = 0u;
      float2 sc = *(const float2*)(scores + i);
      bce0 = fmaxf(sc.x, 0.f) + log1pf(__expf(-fabsf(sc.x))) +
             fmaxf(sc.y, 0.f) + log1pf(__expf(-fabsf(sc.y)));
    } else if (n0 + 1 < N) {
      iou_bits[i] = 0u; iou_bits[i + 1] = 0u;
      float sa = scores[i], sb = scores[i + 1];
      bce0 = fmaxf(sa, 0.f) + log1pf(__expf(-fabsf(sa))) +
             fmaxf(sb, 0.f) + log1pf(__expf(-fabsf(sb)));
    } else {
      iou_bits[i] = 0u;
      float sc = scores[i];
      bce0 = fmaxf(sc, 0.f) + log1pf(__expf(-fabsf(sc)));
    }
  }

  // ---- phase 1: 4 sides; per side: coalesced stage (2KB/row) -> EV x2 ----
  const int tcol = 2 * tid;
  float ev_a[4], ev_b[4];  // statically indexed (full unroll)
#pragma unroll
  for (int s = 0; s < 4; ++s) {
    const float* gside = boxes + (size_t)(b * 64 + s * 16) * Ns;
    if (!tail) {
#pragma unroll
      for (int k = 0; k < 8; ++k) {
        int idx = tid + (k << 8);
        int r = idx >> 7;
        int c = (idx & 127) << 2;
        *(float4*)&tile[r][c] = *(const float4*)(gside + (size_t)r * Ns + a0 + c);
      }
    } else {
#pragma unroll
      for (int k = 0; k < 8; ++k) {
        int idx = tid + (k << 8);
        int r = idx >> 7;
        int c = (idx & 127) << 2;
        int gc = a0 + c;
        if (gc > N - 4) gc = N - 4;  // dup-clamp: invalid anchors pred-guarded
        if (gc < 0) gc = 0;
        *(float4*)&tile[r][c] = *(const float4*)(gside + (size_t)r * Ns + gc);
      }
    }
    __syncthreads();
    // two interleaved softmax-EV chains from LDS (float2 per row)
    float2 x0 = *(const float2*)&tile[0][tcol];
    float2 x1 = *(const float2*)&tile[1][tcol];
    float2 x2 = *(const float2*)&tile[2][tcol];
    float2 x3 = *(const float2*)&tile[3][tcol];
    float2 x4 = *(const float2*)&tile[4][tcol];
    float2 x5 = *(const float2*)&tile[5][tcol];
    float2 x6 = *(const float2*)&tile[6][tcol];
    float2 x7 = *(const float2*)&tile[7][tcol];
    float2 x8 = *(const float2*)&tile[8][tcol];
    float2 x9 = *(const float2*)&tile[9][tcol];
    float2 x10 = *(const float2*)&tile[10][tcol];
    float2 x11 = *(const float2*)&tile[11][tcol];
    float2 x12 = *(const float2*)&tile[12][tcol];
    float2 x13 = *(const float2*)&tile[13][tcol];
    float2 x14 = *(const float2*)&tile[14][tcol];
    float2 x15 = *(const float2*)&tile[15][tcol];
    float mxa = fmaxf(fmaxf(fmaxf(fmaxf(x0.x, x1.x), fmaxf(x2.x, x3.x)),
                            fmaxf(fmaxf(x4.x, x5.x), fmaxf(x6.x, x7.x))),
                      fmaxf(fmaxf(fmaxf(x8.x, x9.x), fmaxf(x10.x, x11.x)),
                            fmaxf(fmaxf(x12.x, x13.x), fmaxf(x14.x, x15.x))));
    float mxb = fmaxf(fmaxf(fmaxf(fmaxf(x0.y, x1.y), fmaxf(x2.y, x3.y)),
                            fmaxf(fmaxf(x4.y, x5.y), fmaxf(x6.y, x7.y))),
                      fmaxf(fmaxf(fmaxf(x8.y, x9.y), fmaxf(x10.y, x11.y)),
                            fmaxf(fmaxf(x12.y, x13.y), fmaxf(x14.y, x15.y))));
    float sa = 0.f, wa = 0.f, sb = 0.f, wb = 0.f, e;
#define STEP(K, XK)                                    \
    e = __expf(XK.x - mxa); sa += e; wa += (float)K * e; \
    e = __expf(XK.y - mxb); sb += e; wb += (float)K * e;
    STEP(0, x0) STEP(1, x1) STEP(2, x2) STEP(3, x3)
    STEP(4, x4) STEP(5, x5) STEP(6, x6) STEP(7, x7)
    STEP(8, x8) STEP(9, x9) STEP(10, x10) STEP(11, x11)
    STEP(12, x12) STEP(13, x13) STEP(14, x14) STEP(15, x15)
#undef STEP
    ev_a[s] = wa * frcp(sa);
    ev_b[s] = wb * frcp(sb);
    __syncthreads();  // tile reads done before restage / heap use
  }

  // ---- screen + ballot compaction (two rounds: anchor n0, n0+1) ----
  {
    bool pa = false, pb = false;
    float ata = 0.f, atb = 0.f;
    if (n0 < N) {
      float w1 = ev_a[2] - ev_a[0], h1 = ev_a[3] - ev_a[1];
      if (w1 > 0.f && h1 > 0.f) { pa = true; ata = atanf(w1 * frcp(h1 + EPSQ)); }
    }
    if (n0 + 1 < N) {
      float w1 = ev_b[2] - ev_b[0], h1 = ev_b[3] - ev_b[1];
      if (w1 > 0.f && h1 > 0.f) { pb = true; atb = atanf(w1 * frcp(h1 + EPSQ)); }
    }
    unsigned long long ma = __ballot(pa);
    int ca = __popcll(ma);
    int sa_ = 0;
    if (l == 0 && ca) sa_ = atomicAdd(&s_cnt, ca);
    sa_ = __shfl(sa_, 0, 64);
    if (pa) {
      int pos = sa_ + __popcll(ma & ((1ull << l) - 1ull));
      s_sv[pos] = make_float4(ev_a[0], ev_a[1], ev_a[2], ev_a[3]);
      s_at[pos] = ata;
      s_ix[pos] = n0;
    }
    unsigned long long mb = __ballot(pb);
    int cb = __popcll(mb);
    int sb_ = 0;
    if (l == 0 && cb) sb_ = atomicAdd(&s_cnt, cb);
    sb_ = __shfl(sb_, 0, 64);
    if (pb) {
      int pos = sb_ + __popcll(mb & ((1ull << l) - 1ull));
      s_sv[pos] = make_float4(ev_b[0], ev_b[1], ev_b[2], ev_b[3]);
      s_at[pos] = atb;
      s_ix[pos] = n0 + 1;
    }
  }
#pragma unroll
  for (int d = 1; d < 64; d <<= 1) bce0 += __shfl_xor(bce0, d, 64);
  if (l == 0) atomicAdd(&s_bce, bce0);
  __syncthreads();
  const int nsurv = s_cnt;
  if (tid == 0) bcePartial[blockIdx.x] = s_bce;  // always written: no memset

  // ---- phase 2: lane = target; wave w scans its survivor quarter ----
  const float4 t = ((const float4*)targets)[b * MQ + l];
  const float x21 = t.x, y21 = t.y, x22 = t.z, y22 = t.w;
  const float w2 = x22 - x21, h2 = y22 - y21;
  const float atan_t = atanf(w2 * frcp(h2 + EPSQ));
  const float area2 = w2 * h2, sumx2 = x21 + x22, sumy2 = y21 + y22;
  const float CPI = 4.0f / (float)(M_PI * M_PI);

  float hv0 = 0.f, hv1 = 0.f, hv2 = 0.f, hv3 = 0.f, hv4 = 0.f;
  float hv5 = 0.f, hv6 = 0.f, hv7 = 0.f, hv8 = 0.f, hv9 = 0.f;
  int hi0 = 0, hi1 = 0, hi2 = 0, hi3 = 0, hi4 = 0;
  int hi5 = 0, hi6 = 0, hi7 = 0, hi8 = 0, hi9 = 0;

  const int qlen = (nsurv + 3) >> 2;
  const int j0 = w * qlen;
  const int j1 = min(nsurv, j0 + qlen);
  for (int j = j0; j < j1; ++j) {
    float4 p = s_sv[j];  // same addr across lanes -> LDS broadcast
    float pa = s_at[j];
    int ixj = s_ix[j];
    float x11 = p.x, y11 = p.y, x12 = p.z, y12 = p.w;
    float w1 = x12 - x11, h1 = y12 - y11;
    float iw = fmaxf(fminf(x12, x22) - fmaxf(x11, x21), 0.f);
    float ih = fmaxf(fminf(y12, y22) - fmaxf(y11, y21), 0.f);
    float inter = iw * ih;
    float uni = w1 * h1 + area2 - inter + EPSQ;
    float iou = inter * frcp(uni);
    float cw = fmaxf(x12, x22) - fminf(x11, x21);
    float ch = fmaxf(y12, y22) - fminf(y11, y21);
    float c2 = cw * cw + ch * ch + EPSQ;
    float dx = sumx2 - x11 - x12;
    float dy = sumy2 - y11 - y12;
    float rho2 = (dx * dx + dy * dy) * 0.25f;
    float da = atan_t - pa;
    float v = CPI * da * da;
    float alpha = v * frcp(v - iou + 1.f + EPSQ);
    float ciou = iou - rho2 * frcp(c2) - alpha * v;
    if (ciou > hv9) {
      float cv = ciou;
      int ci = ixj;
#define INS(vk, ik)                         \
  {                                         \
    bool gt = cv > vk;                      \
    float tv_ = vk; int ti_ = ik;           \
    vk = gt ? cv : vk; ik = gt ? ci : ik;   \
    cv = gt ? tv_ : cv; ci = gt ? ti_ : ci; \
  }
      INS(hv0, hi0) INS(hv1, hi1) INS(hv2, hi2) INS(hv3, hi3) INS(hv4, hi4)
      INS(hv5, hi5) INS(hv6, hi6) INS(hv7, hi7) INS(hv8, hi8) INS(hv9, hi9)
#undef INS
    }
  }
  const int hb = (w * MQ + l) * KTOP;
  s_hv[hb + 0] = hv0; s_hi[hb + 0] = hi0;
  s_hv[hb + 1] = hv1; s_hi[hb + 1] = hi1;
  s_hv[hb + 2] = hv2; s_hi[hb + 2] = hi2;
  s_hv[hb + 3] = hv3; s_hi[hb + 3] = hi3;
  s_hv[hb + 4] = hv4; s_hi[hb + 4] = hi4;
  s_hv[hb + 5] = hv5; s_hi[hb + 5] = hi5;
  s_hv[hb + 6] = hv6; s_hi[hb + 6] = hi6;
  s_hv[hb + 7] = hv7; s_hi[hb + 7] = hi7;
  s_hv[hb + 8] = hv8; s_hi[hb + 8] = hi8;
  s_hv[hb + 9] = hv9; s_hi[hb + 9] = hi9;
  __syncthreads();

  // ---- phase 3: wave 0, lane m: 4-way merge -> s_mg ----
  if (w == 0) {
    const int m = l;
    int p0 = 0, p1 = 0, p2 = 0, p3 = 0;
    for (int r = 0; r < KTOP; ++r) {
      float c0 = s_hv[(0 * MQ + m) * KTOP + p0];
      float c1 = s_hv[(1 * MQ + m) * KTOP + p1];
      float c2m = s_hv[(2 * MQ + m) * KTOP + p2];
      float c3 = s_hv[(3 * MQ + m) * KTOP + p3];
      float best = c0; int bw = 0;
      if (c1 > best) { best = c1; bw = 1; }
      if (c2m > best) { best = c2m; bw = 2; }
      if (c3 > best) { best = c3; bw = 3; }
      int psel = (bw == 0) ? p0 : (bw == 1) ? p1 : (bw == 2) ? p2 : p3;
      int bidx = s_hi[(bw * MQ + m) * KTOP + psel];
      s_mg[m * KTOP + r] = make_uint2(__float_as_uint(best), (unsigned)bidx);
      if (bw == 0) p0 = min(p0 + 1, KTOP - 1);
      else if (bw == 1) p1 = min(p1 + 1, KTOP - 1);
      else if (bw == 2) p2 = min(p2 + 1, KTOP - 1);
      else p3 = min(p3 + 1, KTOP - 1);
    }
  }
  __syncthreads();
  // copy-out: CONTIGUOUS per-block store (merge takes the strided read side)
  uint2* obase = cand + (size_t)(b * bpb + blk) * (MQ * KTOP);
  for (int sl = tid; sl < MQ * KTOP; sl += 256) obase[sl] = s_mg[sl];
}

// ---------------- exact top-10 of LDS buffer (wave 0 only) ----------------
__device__ __forceinline__ void select_top10(
    float* s_bv, int* s_bi, float* s_winv, int* s_wini,
    int* s_cnt, int c, int tid) {
  if (tid < 64) {
    for (int r = 0; r < KTOP; ++r) {
      float bv = 0.f;
      int bs = 0xffff;
      for (int sl = tid; sl < c; sl += 64) {
        float v = s_bv[sl];
        if (v > bv) { bv = v; bs = sl; }
      }
      unsigned long long key =
          ((unsigned long long)__float_as_uint(bv) << 32) | (unsigned int)bs;
#pragma unroll
      for (int d = 1; d < 64; d <<= 1) {
        unsigned long long o = __shfl_xor(key, d, 64);
        if (o > key) key = o;
      }
      if (tid == 0) {
        float wv = __uint_as_float((unsigned int)(key >> 32));
        int ws = (int)(key & 0xffffu);
        s_winv[r] = wv;
        if (wv > 0.f && ws != 0xffff) {
          s_wini[r] = s_bi[ws];
          s_bv[ws] = 0.f;
        } else {
          s_wini[r] = 0;
        }
      }
    }
    if (tid < KTOP) { s_bv[tid] = s_winv[tid]; s_bi[tid] = s_wini[tid]; }
    if (tid == 0) *s_cnt = KTOP;
  }
}

// ---------------- kernel 2: merge 67x10 per (b,m) -> top-10; scatter + exact delta;
// last block finalizes with a parallel reduction ----------------
__global__ __launch_bounds__(256) void merge_kernel(
    const uint2* __restrict__ cand, const float* __restrict__ scores,
    unsigned int* __restrict__ iou_bits, const float* __restrict__ bcePartial,
    float* __restrict__ mergePartial, unsigned int* __restrict__ ctr,
    float* __restrict__ out, int N, int bpb) {
  const int bm = blockIdx.x;
  const int b = bm >> 6;
  const int m = bm & 63;
  const int tid = threadIdx.x;
  const int l = tid & 63;
  const int NC = bpb * KTOP;  // 670 for N=34000

  __shared__ float s_bv[MBUF];
  __shared__ int s_bi[MBUF];
  __shared__ float s_winv[KTOP];
  __shared__ int s_wini[KTOP];
  __shared__ int s_cnt;
  __shared__ float s_d[3];
  __shared__ int s_last;
  __shared__ float s_acc[BQ * 3];  // finalize: {box_sum, npos, bce} per batch
  if (tid == 0) s_cnt = 0;
  if (tid < 3) s_d[tid] = 0.f;
  if (tid < BQ * 3) s_acc[tid] = 0.f;
  __syncthreads();

  // strided gather over decode blocks (cand in contiguous-per-block layout)
  for (int k2 = tid; k2 < NC; k2 += 256) {
    int blkk = k2 / KTOP;
    int r = k2 - blkk * KTOP;
    uint2 e = cand[((size_t)(b * bpb + blkk) * MQ + m) * KTOP + r];
    float v = __uint_as_float(e.x);
    bool p = v > 0.f;
    unsigned long long mask = __ballot(p);  // lane0 active whenever any lane is
    int cnt = __popcll(mask);
    int bslot = 0;
    if (l == 0 && cnt) bslot = atomicAdd(&s_cnt, cnt);
    bslot = __shfl(bslot, 0, 64);
    if (p) {
      int pos = bslot + __popcll(mask & ((1ull << l) - 1ull));
      s_bv[pos] = v;
      s_bi[pos] = (int)e.y;
    }
  }
  __syncthreads();
  int c = s_cnt;
  __syncthreads();
  if (c > KTOP) {
    select_top10(s_bv, s_bi, s_winv, s_wini, &s_cnt, c, tid);
    __syncthreads();
    c = KTOP;
  }
  if (tid < KTOP && tid < c) {
    float v = s_bv[tid];
    if (v > 0.f) {
      int ix = s_bi[tid];
      unsigned int vb = __float_as_uint(v);
      unsigned int old = atomicMax(&iou_bits[(size_t)b * N + ix], vb);
      if (old < vb) {  // raised this anchor's max: exact delta (telescopes)
        float vold = __uint_as_float(old);  // 0.f when old==0
        bool was = (old != 0u);
        atomicAdd(&s_d[0], was ? (vold - v) : (1.f - v));
        if (!was) atomicAdd(&s_d[1], 1.f);
        atomicAdd(&s_d[2], -scores[(size_t)b * N + ix] * (v - vold));
      }
    }
  }
  __syncthreads();
  if (tid == 0) {
    float4* mp = (float4*)(mergePartial + (size_t)bm * 4);
    *mp = make_float4(s_d[0], s_d[1], s_d[2], 0.f);  // always written
    __threadfence();                                  // release partials
    unsigned int done = atomicAdd(ctr, 1u);           // device-scope RMW
    s_last = (done == (unsigned)(gridDim.x - 1)) ? 1 : 0;
  }
  __syncthreads();
  if (s_last) {
    __threadfence();  // acquire: all other blocks' partials now visible
    volatile const float* mp = mergePartial;
    for (int i = tid; i < BQ * MQ; i += 256) {
      int bb = i >> 6;
      float a0 = mp[i * 4 + 0];
      float a1 = mp[i * 4 + 1];
      float a2 = mp[i * 4 + 2];
      atomicAdd(&s_acc[bb * 3 + 0], a0);
      atomicAdd(&s_acc[bb * 3 + 1], a1);
      atomicAdd(&s_acc[bb * 3 + 2], a2);
    }
    volatile const float* bp = bcePartial;
    for (int i = tid; i < BQ * bpb; i += 256) {
      int bb = i / bpb;
      atomicAdd(&s_acc[bb * 3 + 2], bp[i]);
    }
    __syncthreads();
    if (tid == 0) {
      float box = 0.f, obj = 0.f;
      for (int bb = 0; bb < BQ; ++bb) {
        float np = s_acc[bb * 3 + 1];
        box += (np > 0.f) ? s_acc[bb * 3 + 0] / fmaxf(np, 1.f) : 0.f;
        obj += s_acc[bb * 3 + 2] / (float)N;
      }
      out[0] = (7.5f * box + obj) / (float)BQ;
      out[1] = box;
      out[2] = obj;
    }
  }
}

extern "C" void kernel_launch(void* const* d_in, const int* in_sizes, int n_in,
                              void* d_out, int out_size, void* d_ws, size_t ws_size,
                              hipStream_t stream) {
  const float* boxes = (const float*)d_in[0];
  const float* scores = (const float*)d_in[1];
  const float* targets = (const float*)d_in[2];
  float* out = (float*)d_out;
  const int N = in_sizes[1] / BQ;  // scores is [B, N]

  const int bpb = (N + APB - 1) / APB;  // 67 for N=34000
  const int nblk = BQ * bpb;            // 536 decode blocks (<= 768 capacity)

  char* ws = (char*)d_ws;
  size_t cand_bytes = (size_t)BQ * bpb * MQ * KTOP * sizeof(uint2);
  size_t iou_bytes = (size_t)BQ * N * sizeof(unsigned int);
  size_t bce_bytes = (((size_t)nblk * sizeof(float)) + 255) & ~(size_t)255;
  size_t mp_bytes = (size_t)BQ * MQ * 4 * sizeof(float);

  uint2* cand = (uint2*)ws;                    ws += cand_bytes;
  unsigned int* iou_bits = (unsigned int*)ws;  ws += iou_bytes;
  float* bcePartial = (float*)ws;              ws += bce_bytes;
  float* mergePartial = (float*)ws;            ws += mp_bytes;
  unsigned int* ctr = (unsigned int*)ws;

  // 2 dispatches: no memset (always-written per-block partials; ctr zeroed by
  // decode which fully precedes merge by stream order), no finalize dispatch
  // (folded into merge's last block, parallel-reduced).
  decode_topk_kernel<<<nblk, 256, 0, stream>>>(boxes, scores, targets,
                                               iou_bits, cand, bcePartial, ctr, N, bpb);
  merge_kernel<<<BQ * MQ, 256, 0, stream>>>(cand, scores, iou_bits, bcePartial,
                                            mergePartial, ctr, out, N, bpb);
}